// Round 13
// baseline (175.344 us; speedup 1.0000x reference)
//
#include <hip/hip_runtime.h>
#include <hip/hip_bf16.h>

typedef __attribute__((ext_vector_type(8))) short bf16x8;
typedef __attribute__((ext_vector_type(4))) float f32x4;
typedef __attribute__((ext_vector_type(16))) float f32x16;
typedef __attribute__((ext_vector_type(4))) unsigned short ushort4v;

// 0.125 * log2(e): folded into Q so attention probs are exp2(QK) directly
#define QSCALE 0.1803368801111204f

__device__ __forceinline__ unsigned short f2bf(float f) {
  union { float f; unsigned int u; } x; x.f = f;
  unsigned int u = x.u;
  unsigned int r = (u + 0x7fffu + ((u >> 16) & 1u)) >> 16;
  return (unsigned short)r;
}

// async global->LDS 16B copy (global_load_lds_dwordx4)
__device__ __forceinline__ void gll16(const unsigned short* g, unsigned short* l) {
  __builtin_amdgcn_global_load_lds(
      (const __attribute__((address_space(1))) unsigned int*)g,
      (__attribute__((address_space(3))) unsigned int*)l, 16, 0, 0);
}

// ---- fused prep: z<4 transpose+convert weights; z==4 convert x ----
__global__ __launch_bounds__(256) void prep_kernel(
    const float* __restrict__ x,
    const float* __restrict__ Wq, const float* __restrict__ Wk,
    const float* __restrict__ Wv, const float* __restrict__ Wo,
    unsigned short* __restrict__ xb,
    unsigned short* __restrict__ QKVt, unsigned short* __restrict__ Wot) {
  int z = blockIdx.z;
  if (z == 4) {  // x: 4096x1024 fp32 -> bf16
    size_t base = ((size_t)(blockIdx.y * 32 + blockIdx.x)) * 4096 + threadIdx.x * 16;
#pragma unroll
    for (int c = 0; c < 4; ++c) {
      float4 v = *(const float4*)(x + base + c * 4);
      ushort4v o = { f2bf(v.x), f2bf(v.y), f2bf(v.z), f2bf(v.w) };
      *(ushort4v*)(xb + base + c * 4) = o;
    }
    return;
  }
  __shared__ float t[32][33];
  const float* src;
  unsigned short* dst;
  int C, rowoff;
  if (z == 0)      { src = Wq; dst = QKVt; C = 1024; rowoff = 0; }
  else if (z == 1) { src = Wk; dst = QKVt; C = 64;   rowoff = 1024; }
  else if (z == 2) { src = Wv; dst = QKVt; C = 64;   rowoff = 1088; }
  else             { src = Wo; dst = Wot;  C = 1024; rowoff = 0; }
  int c0 = blockIdx.x * 32, r0 = blockIdx.y * 32;
  if (c0 >= C) return;
  int tx = threadIdx.x & 31, ty = threadIdx.x >> 5;
#pragma unroll
  for (int i = 0; i < 32; i += 8)
    t[ty + i][tx] = src[(size_t)(r0 + ty + i) * C + c0 + tx];
  __syncthreads();
#pragma unroll
  for (int i = 0; i < 32; i += 8)
    dst[(size_t)(rowoff + c0 + ty + i) * 1024 + r0 + tx] = f2bf(t[tx][ty + i]);
}

// ------- bf16 MFMA GEMM: C[M][N] = A[M][K] @ Bt[N][K]^T + bias -------
// 64x64 tile / 256 thr / 4 waves, BK=64: 16 K-steps (was 32), 8 MFMA per
// wave per step (was 4) -- halves the count of barrier+staging latency
// events (the dominant cost at these small shapes; cf. m102 shape-curve
// floor) while doubling per-step compute. LDS 2 bufs x (8KB A + 8KB B) =
// 32 KB -> 5 blocks/CU (R3's BK=64 failure was at 72 KB/2 blocks; R9
// showed 4+ blocks/CU is the TLP regime that works). 128B rows need the
// full 8-way chunk-XOR swizzle: physical chunk pc = lc ^ (row&7)
// (lc = kk*4+quad); consecutive 8 lanes hit 8 distinct bank-groups.
// Rule 21: LDS dest linear (gll16), global source chunk pre-swizzled
// (per-8-thread group still covers one 128B segment -> coalesced).
// QKVMODE: per-column bias select + QSCALE on Q cols; V cols scatter V^T.
template <typename OutT, bool QKVMODE>
__global__ __launch_bounds__(256, 4) void gemm_bf16_kernel(
    const unsigned short* __restrict__ A, const unsigned short* __restrict__ Bt,
    const float* __restrict__ b0, const float* __restrict__ b1,
    const float* __restrict__ b2, OutT* __restrict__ C,
    unsigned short* __restrict__ Vt, int M, int N, int K) {
  __shared__ __align__(16) unsigned short As[2][64 * 64];
  __shared__ __align__(16) unsigned short Bs[2][64 * 64];
  int tid = threadIdx.x;
  int wid = tid >> 6, lane = tid & 63;
  int l15 = lane & 15, quad = lane >> 4;
  int m0 = blockIdx.x * 64, n0 = blockIdx.y * 64;
  int mw = (wid >> 1) * 32, nw = (wid & 1) * 32;
  f32x4 acc[2][2];
#pragma unroll
  for (int i = 0; i < 2; i++)
#pragma unroll
    for (int j = 0; j < 2; j++)
#pragma unroll
      for (int e = 0; e < 4; ++e) acc[i][j][e] = 0.f;

  // staging: 512 16B chunks per matrix per tile; thread u owns chunks u
  // and u+256. chunk c: row=c>>3, phys chunk pch=c&7, global chunk
  // gq = pch ^ (row&7) (inverse swizzle; involution).
  int c0i = tid, c1i = tid + 256;
  int r0 = c0i >> 3, g0 = (c0i & 7) ^ (r0 & 7);
  int r1 = c1i >> 3, g1 = (c1i & 7) ^ (r1 & 7);
  const unsigned short* Ag0 = A + (size_t)(m0 + r0) * K + g0 * 8;
  const unsigned short* Ag1 = A + (size_t)(m0 + r1) * K + g1 * 8;
  const unsigned short* Bg0 = Bt + (size_t)(n0 + r0) * K + g0 * 8;
  const unsigned short* Bg1 = Bt + (size_t)(n0 + r1) * K + g1 * 8;

#define STG(buf, koff)                            \
  do {                                            \
    gll16(Ag0 + (koff), As[buf] + c0i * 8);       \
    gll16(Ag1 + (koff), As[buf] + c1i * 8);       \
    gll16(Bg0 + (koff), Bs[buf] + c0i * 8);       \
    gll16(Bg1 + (koff), Bs[buf] + c1i * 8);       \
  } while (0)

  int nstep = K >> 6;  // 16 for K=1024
  STG(0, 0);

  for (int it = 0; it < nstep; ++it) {
    int cur = it & 1;
    if (it + 1 < nstep) {
      STG(cur ^ 1, (it + 1) * 64);
      asm volatile("s_waitcnt vmcnt(4)" ::: "memory");  // current tile done
    } else {
      asm volatile("s_waitcnt vmcnt(0)" ::: "memory");
    }
    __builtin_amdgcn_s_barrier();
    __builtin_amdgcn_sched_barrier(0);
    const unsigned short* Asb = As[cur];
    const unsigned short* Bsb = Bs[cur];
#pragma unroll
    for (int kk = 0; kk < 2; ++kk) {
      bf16x8 af[2], bfr[2];
#pragma unroll
      for (int t = 0; t < 2; ++t) {
        int row = mw + t * 16 + l15;
        int pc = (kk * 4 + quad) ^ (row & 7);
        af[t] = *(const bf16x8*)(Asb + row * 64 + pc * 8);
      }
#pragma unroll
      for (int t = 0; t < 2; ++t) {
        int row = nw + t * 16 + l15;
        int pc = (kk * 4 + quad) ^ (row & 7);
        bfr[t] = *(const bf16x8*)(Bsb + row * 64 + pc * 8);
      }
#pragma unroll
      for (int mt = 0; mt < 2; ++mt)
#pragma unroll
        for (int nt = 0; nt < 2; ++nt)
          acc[mt][nt] = __builtin_amdgcn_mfma_f32_16x16x32_bf16(
              af[mt], bfr[nt], acc[mt][nt], 0, 0, 0);
    }
    asm volatile("s_waitcnt lgkmcnt(0)" ::: "memory");
    __builtin_amdgcn_sched_barrier(0);
    __builtin_amdgcn_s_barrier();
  }
#undef STG

#pragma unroll
  for (int mt = 0; mt < 2; ++mt)
#pragma unroll
    for (int nt = 0; nt < 2; ++nt) {
      int col = n0 + nw + nt * 16 + l15;
      float bias, cs;
      if constexpr (QKVMODE) {
        bias = (col < 1024) ? b0[col] : ((col < 1088) ? b1[col - 1024] : b2[col - 1088]);
        cs = (col < 1024) ? QSCALE : 1.0f;
      } else {
        bias = b0[col];
        cs = 1.0f;
      }
#pragma unroll
      for (int r = 0; r < 4; ++r) {
        int row = m0 + mw + mt * 16 + quad * 4 + r;
        float v = (acc[mt][nt][r] + bias) * cs;
        if constexpr (sizeof(OutT) == 2)
          C[(size_t)row * N + col] = f2bf(v);
        else
          C[(size_t)row * N + col] = v;
        if constexpr (QKVMODE) {
          if (col >= 1088)  // scatter V^T for flash: Vt[b*64+d][s]
            Vt[((size_t)(row >> 11) * 64 + (col - 1088)) * 2048 + (row & 2047)] =
                f2bf(v);
        }
      }
    }
}

// ---------------- flash attention (MQA, split-K in-block) ----------------
// EXACT R12 version (best measured: 46.2 us, 56 VGPR). T12 swapped-QK +
// in-register P; LDS double-buffer with ONE barrier per kt-tile (trailing
// barrier provably redundant under dbuf); T5 setprio around MFMA clusters.
__global__ __launch_bounds__(512, 2) void flash_attn_kernel(
    const unsigned short* __restrict__ QKV,  // [B*S][1152] bf16: Q|K|V
    const unsigned short* __restrict__ Vt,   // [B][64][2048] bf16
    unsigned short* __restrict__ AO) {       // [B*S][1024] bf16
  constexpr int S = 2048, LDQ = 1152;
  constexpr int PK = 72;
  // [tilebuf][slice][K=0/V=1][64*PK] = 73728 B
  __shared__ __align__(16) unsigned short smem[2][2][2][64 * PK];
  int tid = threadIdx.x;
  int wid = tid >> 6, lane = tid & 63;
  int l31 = lane & 31, half = lane >> 5;
  int p = wid & 3, ks = wid >> 2;
  int q0 = blockIdx.x * 128, h = blockIdx.y, b = blockIdx.z;

  // Q frags (MFMA B operand; n=q=l31, k(d)=s*16+half*8+j)
  const unsigned short* Qb =
      QKV + (size_t)(b * S + q0 + p * 32 + l31) * LDQ + h * 64 + half * 8;
  bf16x8 qf[4];
#pragma unroll
  for (int f = 0; f < 4; ++f) qf[f] = *(const bf16x8*)(Qb + f * 16);

  // staging role: 256 threads per slice sl; each stages 2 K + 2 V b128 chunks
  int u = tid & 255, sl = tid >> 8;
  int srow = u >> 2, sc = (u & 3) * 8;  // chunks at cols sc and sc+32
  const unsigned short* Kgb = QKV + ((size_t)b * S) * LDQ + 1024;
  const unsigned short* Vgb = Vt + ((size_t)(b * 64 + srow)) * 2048;

  f32x16 oa0, oa1;
#pragma unroll
  for (int r = 0; r < 16; ++r) { oa0[r] = 0.f; oa1[r] = 0.f; }
  float rs = 0.f;  // per-lane partial row-sum for q=l31

  int kb0 = sl * 1024;
  bf16x8 ka = *(const bf16x8*)(Kgb + (size_t)(kb0 + srow) * LDQ + sc);
  bf16x8 kc = *(const bf16x8*)(Kgb + (size_t)(kb0 + srow) * LDQ + sc + 32);
  bf16x8 va = *(const bf16x8*)(Vgb + kb0 + sc);
  bf16x8 vc = *(const bf16x8*)(Vgb + kb0 + sc + 32);

  for (int kt = 0; kt < 16; ++kt) {
    int tb = kt & 1;
    // stage this tile into buffer tb (both slices across the 512 threads)
    *(bf16x8*)(smem[tb][sl][0] + srow * PK + sc) = ka;
    *(bf16x8*)(smem[tb][sl][0] + srow * PK + sc + 32) = kc;
    *(bf16x8*)(smem[tb][sl][1] + srow * PK + sc) = va;
    *(bf16x8*)(smem[tb][sl][1] + srow * PK + sc + 32) = vc;
    __syncthreads();  // publishes tile kt; fences buffer tb for reuse
    if (kt + 1 < 16) {  // prefetch next tile; in flight across compute
      int kbn = sl * 1024 + (kt + 1) * 64;
      ka = *(const bf16x8*)(Kgb + (size_t)(kbn + srow) * LDQ + sc);
      kc = *(const bf16x8*)(Kgb + (size_t)(kbn + srow) * LDQ + sc + 32);
      va = *(const bf16x8*)(Vgb + kbn + sc);
      vc = *(const bf16x8*)(Vgb + kbn + sc + 32);
    }
    const unsigned short* Ksb = smem[tb][ks][0];
    const unsigned short* Vsb = smem[tb][ks][1];

    // S^T = K.Q^T : C col=q=l31, row=key=(r&3)+8*(r>>2)+4*half (+32*n2)
#pragma unroll
    for (int n2 = 0; n2 < 2; ++n2) {
      f32x16 sacc;
#pragma unroll
      for (int i = 0; i < 16; ++i) sacc[i] = 0.f;
      __builtin_amdgcn_s_setprio(1);
#pragma unroll
      for (int s = 0; s < 4; ++s) {
        bf16x8 kf =
            *(const bf16x8*)(Ksb + (n2 * 32 + l31) * PK + s * 16 + half * 8);
        sacc = __builtin_amdgcn_mfma_f32_32x32x16_bf16(kf, qf[s], sacc, 0, 0, 0);
      }
      __builtin_amdgcn_s_setprio(0);
      // two key-16-slices per n2: sg = n2*2 + t covers keys sg*16..+15
#pragma unroll
      for (int t = 0; t < 2; ++t) {
        float pr[8];
#pragma unroll
        for (int j = 0; j < 8; ++j) {
          pr[j] = __builtin_amdgcn_exp2f(sacc[t * 8 + j]);
          rs += pr[j];
        }
        unsigned w0A, w1A, w0B, w1B;
        asm("v_cvt_pk_bf16_f32 %0, %1, %2" : "=v"(w0A) : "v"(pr[0]), "v"(pr[1]));
        asm("v_cvt_pk_bf16_f32 %0, %1, %2" : "=v"(w1A) : "v"(pr[2]), "v"(pr[3]));
        asm("v_cvt_pk_bf16_f32 %0, %1, %2" : "=v"(w0B) : "v"(pr[4]), "v"(pr[5]));
        asm("v_cvt_pk_bf16_f32 %0, %1, %2" : "=v"(w1B) : "v"(pr[6]), "v"(pr[7]));
        asm volatile("v_permlane32_swap_b32 %0, %1" : "+v"(w0A), "+v"(w0B));
        asm volatile("v_permlane32_swap_b32 %0, %1" : "+v"(w1A), "+v"(w1B));
        union { unsigned u[4]; bf16x8 v; } afu;
        afu.u[0] = w0A; afu.u[1] = w1A; afu.u[2] = w0B; afu.u[3] = w1B;
        int sg = n2 * 2 + t;
        bf16x8 vf0 = *(const bf16x8*)(Vsb + (l31) * PK + sg * 16 + half * 8);
        bf16x8 vf1 = *(const bf16x8*)(Vsb + (32 + l31) * PK + sg * 16 + half * 8);
        __builtin_amdgcn_s_setprio(1);
        oa0 = __builtin_amdgcn_mfma_f32_32x32x16_bf16(afu.v, vf0, oa0, 0, 0, 0);
        oa1 = __builtin_amdgcn_mfma_f32_32x32x16_bf16(afu.v, vf1, oa1, 0, 0, 0);
        __builtin_amdgcn_s_setprio(0);
      }
    }
    // no trailing barrier: next iter writes the OTHER buffer; its top
    // barrier orders this iter's reads before any overwrite of this buffer
  }

  // full row-sum for q=l31: add partner half's key-subset
  float rsf = rs + __shfl_xor(rs, 32, 64);

  // split-K combine via LDS (aliases buffer 0 region; the kt=15 top
  // barrier ordered all buffer-0 reads (kt=14) before these writes)
  float* Cb = (float*)smem;  // [4 groups][32 q][66]: d0..63, rs_ks1, rs_ks0
  if (ks == 1) {
#pragma unroll
    for (int r = 0; r < 16; ++r) {
      int row = (r & 3) + 8 * (r >> 2) + 4 * half;
      Cb[(p * 32 + row) * 66 + l31] = oa0[r];
      Cb[(p * 32 + row) * 66 + 32 + l31] = oa1[r];
    }
    if (half == 0) Cb[(p * 32 + l31) * 66 + 64] = rsf;
  } else {
    if (half == 0) Cb[(p * 32 + l31) * 66 + 65] = rsf;
  }
  __syncthreads();
  if (ks == 0) {
    unsigned short* Ob = AO + (size_t)(b * S + q0 + p * 32) * 1024 + h * 64;
#pragma unroll
    for (int r = 0; r < 16; ++r) {
      int row = (r & 3) + 8 * (r >> 2) + 4 * half;
      float p0 = Cb[(p * 32 + row) * 66 + l31];
      float p1 = Cb[(p * 32 + row) * 66 + 32 + l31];
      float inv = 1.0f / (Cb[(p * 32 + row) * 66 + 64] + Cb[(p * 32 + row) * 66 + 65]);
      Ob[(size_t)row * 1024 + l31] = f2bf((oa0[r] + p0) * inv);
      Ob[(size_t)row * 1024 + 32 + l31] = f2bf((oa1[r] + p1) * inv);
    }
  }
}

extern "C" void kernel_launch(void* const* d_in, const int* in_sizes, int n_in,
                              void* d_out, int out_size, void* d_ws, size_t ws_size,
                              hipStream_t stream) {
  const float* x  = (const float*)d_in[0];
  const float* Wq = (const float*)d_in[1];
  const float* bq = (const float*)d_in[2];
  const float* Wk = (const float*)d_in[3];
  const float* bk = (const float*)d_in[4];
  const float* Wv = (const float*)d_in[5];
  const float* bv = (const float*)d_in[6];
  const float* Wo = (const float*)d_in[7];
  const float* bo = (const float*)d_in[8];
  float* out = (float*)d_out;

  constexpr int B = 2, S = 2048, D = 1024, Dk = 64, H = 16;
  constexpr int M = B * S;          // 4096
  constexpr int NQKV = D + 2 * Dk;  // 1152

  char* ws = (char*)d_ws;
  unsigned short* xb   = (unsigned short*)ws; ws += (size_t)M * D * 2;
  unsigned short* QKVt = (unsigned short*)ws; ws += (size_t)NQKV * D * 2;
  unsigned short* Wot  = (unsigned short*)ws; ws += (size_t)D * D * 2;
  unsigned short* QKV  = (unsigned short*)ws; ws += (size_t)M * NQKV * 2;
  unsigned short* Vtb  = (unsigned short*)ws; ws += (size_t)B * Dk * S * 2;
  unsigned short* AO   = (unsigned short*)ws; ws += (size_t)M * D * 2;

  // 1. prep: convert x (z=4) + transpose/convert 4 weights (z=0..3)
  prep_kernel<<<dim3(32, 32, 5), 256, 0, stream>>>(x, Wq, Wk, Wv, Wo, xb, QKVt, Wot);

  // 2. fused QKV projection (64x64 tiles, BK=64 = 1152 blocks, 5/CU cap);
  //    epilogue scatters V^T and pre-scales Q by 0.125*log2e
  gemm_bf16_kernel<unsigned short, true><<<dim3(M / 64, NQKV / 64), 256, 0, stream>>>(
      xb, QKVt, bq, bk, bv, QKV, Vtb, M, NQKV, D);

  // 3. attention (split-K in-block: 512 blocks x 8 waves, in-register P,
  //    LDS dbuf + single barrier per tile)
  flash_attn_kernel<<<dim3(S / 128, H, B), 512, 0, stream>>>(QKV, Vtb, AO);

  // 4. output projection (64x64 tiles, BK=64 = 1024 blocks)
  gemm_bf16_kernel<float, false><<<dim3(M / 64, D / 64), 256, 0, stream>>>(
      AO, Wot, bo, nullptr, nullptr, out, nullptr, M, D, D);
}

// Round 14
// 167.226 us; speedup vs baseline: 1.0485x; 1.0485x over previous
//
#include <hip/hip_runtime.h>
#include <hip/hip_bf16.h>

typedef __attribute__((ext_vector_type(8))) short bf16x8;
typedef __attribute__((ext_vector_type(4))) float f32x4;
typedef __attribute__((ext_vector_type(16))) float f32x16;
typedef __attribute__((ext_vector_type(4))) unsigned short ushort4v;

// 0.125 * log2(e): folded into Q so attention probs are exp2(QK) directly
#define QSCALE 0.1803368801111204f

__device__ __forceinline__ unsigned short f2bf(float f) {
  union { float f; unsigned int u; } x; x.f = f;
  unsigned int u = x.u;
  unsigned int r = (u + 0x7fffu + ((u >> 16) & 1u)) >> 16;
  return (unsigned short)r;
}

// async global->LDS 16B copy (global_load_lds_dwordx4)
__device__ __forceinline__ void gll16(const unsigned short* g, unsigned short* l) {
  __builtin_amdgcn_global_load_lds(
      (const __attribute__((address_space(1))) unsigned int*)g,
      (__attribute__((address_space(3))) unsigned int*)l, 16, 0, 0);
}

// ---- fused prep: z<4 transpose+convert weights; z==4 convert x ----
__global__ __launch_bounds__(256) void prep_kernel(
    const float* __restrict__ x,
    const float* __restrict__ Wq, const float* __restrict__ Wk,
    const float* __restrict__ Wv, const float* __restrict__ Wo,
    unsigned short* __restrict__ xb,
    unsigned short* __restrict__ QKVt, unsigned short* __restrict__ Wot) {
  int z = blockIdx.z;
  if (z == 4) {  // x: 4096x1024 fp32 -> bf16
    size_t base = ((size_t)(blockIdx.y * 32 + blockIdx.x)) * 4096 + threadIdx.x * 16;
#pragma unroll
    for (int c = 0; c < 4; ++c) {
      float4 v = *(const float4*)(x + base + c * 4);
      ushort4v o = { f2bf(v.x), f2bf(v.y), f2bf(v.z), f2bf(v.w) };
      *(ushort4v*)(xb + base + c * 4) = o;
    }
    return;
  }
  __shared__ float t[32][33];
  const float* src;
  unsigned short* dst;
  int C, rowoff;
  if (z == 0)      { src = Wq; dst = QKVt; C = 1024; rowoff = 0; }
  else if (z == 1) { src = Wk; dst = QKVt; C = 64;   rowoff = 1024; }
  else if (z == 2) { src = Wv; dst = QKVt; C = 64;   rowoff = 1088; }
  else             { src = Wo; dst = Wot;  C = 1024; rowoff = 0; }
  int c0 = blockIdx.x * 32, r0 = blockIdx.y * 32;
  if (c0 >= C) return;
  int tx = threadIdx.x & 31, ty = threadIdx.x >> 5;
#pragma unroll
  for (int i = 0; i < 32; i += 8)
    t[ty + i][tx] = src[(size_t)(r0 + ty + i) * C + c0 + tx];
  __syncthreads();
#pragma unroll
  for (int i = 0; i < 32; i += 8)
    dst[(size_t)(rowoff + c0 + ty + i) * 1024 + r0 + tx] = f2bf(t[tx][ty + i]);
}

// ------- bf16 MFMA GEMM: C[M][N] = A[M][K] @ Bt[N][K]^T + bias -------
// R9/R12 version EXACT (measured-best family optimum): 64x64 tile /
// 256 thr / 4 waves, BK=32, 4-5 blocks/CU, gll16 linear LDS, counted
// vmcnt(2) dbuf, T2 chunk-XOR swizzle (chunk' = quad^((row>>1)&3);
// pre-swizzled global source + swizzled ds_read, rule 21). Nine GEMM
// structures tried across R0-R13 bracket 166-176 us total; this one is
// the optimum and every single-lever deviation (tile, BK, waves, depth,
// fusion) regressed or nulled.
// QKVMODE: per-column bias select + QSCALE on Q cols; V cols scatter V^T.
template <typename OutT, bool QKVMODE>
__global__ __launch_bounds__(256, 4) void gemm_bf16_kernel(
    const unsigned short* __restrict__ A, const unsigned short* __restrict__ Bt,
    const float* __restrict__ b0, const float* __restrict__ b1,
    const float* __restrict__ b2, OutT* __restrict__ C,
    unsigned short* __restrict__ Vt, int M, int N, int K) {
  __shared__ __align__(16) unsigned short As[2][64 * 32];
  __shared__ __align__(16) unsigned short Bs[2][64 * 32];
  int tid = threadIdx.x;
  int wid = tid >> 6, lane = tid & 63;
  int l15 = lane & 15, quad = lane >> 4;
  int m0 = blockIdx.x * 64, n0 = blockIdx.y * 64;
  int mw = (wid >> 1) * 32, nw = (wid & 1) * 32;
  f32x4 acc[2][2];
#pragma unroll
  for (int i = 0; i < 2; i++)
#pragma unroll
    for (int j = 0; j < 2; j++)
#pragma unroll
      for (int e = 0; e < 4; ++e) acc[i][j][e] = 0.f;

  int u = tid;
  int srow = u >> 2;
  int gq = (u & 3) ^ ((srow >> 1) & 3);
  const unsigned short* Ag = A + (size_t)(m0 + srow) * K + gq * 8;
  const unsigned short* Bg = Bt + (size_t)(n0 + srow) * K + gq * 8;

  gll16(Ag, As[0] + u * 8);
  gll16(Bg, Bs[0] + u * 8);

  for (int k0 = 0; k0 < K; k0 += 32) {
    int cur = (k0 >> 5) & 1;
    if (k0 + 32 < K) {
      int nxt = cur ^ 1;
      gll16(Ag + k0 + 32, As[nxt] + u * 8);
      gll16(Bg + k0 + 32, Bs[nxt] + u * 8);
      asm volatile("s_waitcnt vmcnt(2)" ::: "memory");  // current tile done
    } else {
      asm volatile("s_waitcnt vmcnt(0)" ::: "memory");
    }
    __builtin_amdgcn_s_barrier();
    __builtin_amdgcn_sched_barrier(0);
    const unsigned short* Asb = As[cur];
    const unsigned short* Bsb = Bs[cur];
    bf16x8 af[2], bfr[2];
#pragma unroll
    for (int t = 0; t < 2; ++t) {
      int row = mw + t * 16 + l15;
      af[t] = *(const bf16x8*)(Asb + row * 32 + ((quad ^ ((row >> 1) & 3)) * 8));
    }
#pragma unroll
    for (int t = 0; t < 2; ++t) {
      int row = nw + t * 16 + l15;
      bfr[t] = *(const bf16x8*)(Bsb + row * 32 + ((quad ^ ((row >> 1) & 3)) * 8));
    }
#pragma unroll
    for (int mt = 0; mt < 2; ++mt)
#pragma unroll
      for (int nt = 0; nt < 2; ++nt)
        acc[mt][nt] = __builtin_amdgcn_mfma_f32_16x16x32_bf16(
            af[mt], bfr[nt], acc[mt][nt], 0, 0, 0);
    asm volatile("s_waitcnt lgkmcnt(0)" ::: "memory");
    __builtin_amdgcn_sched_barrier(0);
    __builtin_amdgcn_s_barrier();
  }
#pragma unroll
  for (int mt = 0; mt < 2; ++mt)
#pragma unroll
    for (int nt = 0; nt < 2; ++nt) {
      int col = n0 + nw + nt * 16 + l15;
      float bias, cs;
      if constexpr (QKVMODE) {
        bias = (col < 1024) ? b0[col] : ((col < 1088) ? b1[col - 1024] : b2[col - 1088]);
        cs = (col < 1024) ? QSCALE : 1.0f;
      } else {
        bias = b0[col];
        cs = 1.0f;
      }
#pragma unroll
      for (int r = 0; r < 4; ++r) {
        int row = m0 + mw + mt * 16 + quad * 4 + r;
        float v = (acc[mt][nt][r] + bias) * cs;
        if constexpr (sizeof(OutT) == 2)
          C[(size_t)row * N + col] = f2bf(v);
        else
          C[(size_t)row * N + col] = v;
        if constexpr (QKVMODE) {
          if (col >= 1088)  // scatter V^T for flash: Vt[b*64+d][s]
            Vt[((size_t)(row >> 11) * 64 + (col - 1088)) * 2048 + (row & 2047)] =
                f2bf(v);
        }
      }
    }
}

// ---------------- flash attention (MQA, split-K in-block) ----------------
// EXACT R12 version (best measured: 46.2 us, 56 VGPR). T12 swapped-QK +
// in-register P; LDS double-buffer with ONE barrier per kt-tile (trailing
// barrier provably redundant under dbuf); T5 setprio around MFMA clusters.
__global__ __launch_bounds__(512, 2) void flash_attn_kernel(
    const unsigned short* __restrict__ QKV,  // [B*S][1152] bf16: Q|K|V
    const unsigned short* __restrict__ Vt,   // [B][64][2048] bf16
    unsigned short* __restrict__ AO) {       // [B*S][1024] bf16
  constexpr int S = 2048, LDQ = 1152;
  constexpr int PK = 72;
  // [tilebuf][slice][K=0/V=1][64*PK] = 73728 B
  __shared__ __align__(16) unsigned short smem[2][2][2][64 * PK];
  int tid = threadIdx.x;
  int wid = tid >> 6, lane = tid & 63;
  int l31 = lane & 31, half = lane >> 5;
  int p = wid & 3, ks = wid >> 2;
  int q0 = blockIdx.x * 128, h = blockIdx.y, b = blockIdx.z;

  // Q frags (MFMA B operand; n=q=l31, k(d)=s*16+half*8+j)
  const unsigned short* Qb =
      QKV + (size_t)(b * S + q0 + p * 32 + l31) * LDQ + h * 64 + half * 8;
  bf16x8 qf[4];
#pragma unroll
  for (int f = 0; f < 4; ++f) qf[f] = *(const bf16x8*)(Qb + f * 16);

  // staging role: 256 threads per slice sl; each stages 2 K + 2 V b128 chunks
  int u = tid & 255, sl = tid >> 8;
  int srow = u >> 2, sc = (u & 3) * 8;  // chunks at cols sc and sc+32
  const unsigned short* Kgb = QKV + ((size_t)b * S) * LDQ + 1024;
  const unsigned short* Vgb = Vt + ((size_t)(b * 64 + srow)) * 2048;

  f32x16 oa0, oa1;
#pragma unroll
  for (int r = 0; r < 16; ++r) { oa0[r] = 0.f; oa1[r] = 0.f; }
  float rs = 0.f;  // per-lane partial row-sum for q=l31

  int kb0 = sl * 1024;
  bf16x8 ka = *(const bf16x8*)(Kgb + (size_t)(kb0 + srow) * LDQ + sc);
  bf16x8 kc = *(const bf16x8*)(Kgb + (size_t)(kb0 + srow) * LDQ + sc + 32);
  bf16x8 va = *(const bf16x8*)(Vgb + kb0 + sc);
  bf16x8 vc = *(const bf16x8*)(Vgb + kb0 + sc + 32);

  for (int kt = 0; kt < 16; ++kt) {
    int tb = kt & 1;
    // stage this tile into buffer tb (both slices across the 512 threads)
    *(bf16x8*)(smem[tb][sl][0] + srow * PK + sc) = ka;
    *(bf16x8*)(smem[tb][sl][0] + srow * PK + sc + 32) = kc;
    *(bf16x8*)(smem[tb][sl][1] + srow * PK + sc) = va;
    *(bf16x8*)(smem[tb][sl][1] + srow * PK + sc + 32) = vc;
    __syncthreads();  // publishes tile kt; fences buffer tb for reuse
    if (kt + 1 < 16) {  // prefetch next tile; in flight across compute
      int kbn = sl * 1024 + (kt + 1) * 64;
      ka = *(const bf16x8*)(Kgb + (size_t)(kbn + srow) * LDQ + sc);
      kc = *(const bf16x8*)(Kgb + (size_t)(kbn + srow) * LDQ + sc + 32);
      va = *(const bf16x8*)(Vgb + kbn + sc);
      vc = *(const bf16x8*)(Vgb + kbn + sc + 32);
    }
    const unsigned short* Ksb = smem[tb][ks][0];
    const unsigned short* Vsb = smem[tb][ks][1];

    // S^T = K.Q^T : C col=q=l31, row=key=(r&3)+8*(r>>2)+4*half (+32*n2)
#pragma unroll
    for (int n2 = 0; n2 < 2; ++n2) {
      f32x16 sacc;
#pragma unroll
      for (int i = 0; i < 16; ++i) sacc[i] = 0.f;
      __builtin_amdgcn_s_setprio(1);
#pragma unroll
      for (int s = 0; s < 4; ++s) {
        bf16x8 kf =
            *(const bf16x8*)(Ksb + (n2 * 32 + l31) * PK + s * 16 + half * 8);
        sacc = __builtin_amdgcn_mfma_f32_32x32x16_bf16(kf, qf[s], sacc, 0, 0, 0);
      }
      __builtin_amdgcn_s_setprio(0);
      // two key-16-slices per n2: sg = n2*2 + t covers keys sg*16..+15
#pragma unroll
      for (int t = 0; t < 2; ++t) {
        float pr[8];
#pragma unroll
        for (int j = 0; j < 8; ++j) {
          pr[j] = __builtin_amdgcn_exp2f(sacc[t * 8 + j]);
          rs += pr[j];
        }
        unsigned w0A, w1A, w0B, w1B;
        asm("v_cvt_pk_bf16_f32 %0, %1, %2" : "=v"(w0A) : "v"(pr[0]), "v"(pr[1]));
        asm("v_cvt_pk_bf16_f32 %0, %1, %2" : "=v"(w1A) : "v"(pr[2]), "v"(pr[3]));
        asm("v_cvt_pk_bf16_f32 %0, %1, %2" : "=v"(w0B) : "v"(pr[4]), "v"(pr[5]));
        asm("v_cvt_pk_bf16_f32 %0, %1, %2" : "=v"(w1B) : "v"(pr[6]), "v"(pr[7]));
        asm volatile("v_permlane32_swap_b32 %0, %1" : "+v"(w0A), "+v"(w0B));
        asm volatile("v_permlane32_swap_b32 %0, %1" : "+v"(w1A), "+v"(w1B));
        union { unsigned u[4]; bf16x8 v; } afu;
        afu.u[0] = w0A; afu.u[1] = w1A; afu.u[2] = w0B; afu.u[3] = w1B;
        int sg = n2 * 2 + t;
        bf16x8 vf0 = *(const bf16x8*)(Vsb + (l31) * PK + sg * 16 + half * 8);
        bf16x8 vf1 = *(const bf16x8*)(Vsb + (32 + l31) * PK + sg * 16 + half * 8);
        __builtin_amdgcn_s_setprio(1);
        oa0 = __builtin_amdgcn_mfma_f32_32x32x16_bf16(afu.v, vf0, oa0, 0, 0, 0);
        oa1 = __builtin_amdgcn_mfma_f32_32x32x16_bf16(afu.v, vf1, oa1, 0, 0, 0);
        __builtin_amdgcn_s_setprio(0);
      }
    }
    // no trailing barrier: next iter writes the OTHER buffer; its top
    // barrier orders this iter's reads before any overwrite of this buffer
  }

  // full row-sum for q=l31: add partner half's key-subset
  float rsf = rs + __shfl_xor(rs, 32, 64);

  // split-K combine via LDS (aliases buffer 0 region; the kt=15 top
  // barrier ordered all buffer-0 reads (kt=14) before these writes)
  float* Cb = (float*)smem;  // [4 groups][32 q][66]: d0..63, rs_ks1, rs_ks0
  if (ks == 1) {
#pragma unroll
    for (int r = 0; r < 16; ++r) {
      int row = (r & 3) + 8 * (r >> 2) + 4 * half;
      Cb[(p * 32 + row) * 66 + l31] = oa0[r];
      Cb[(p * 32 + row) * 66 + 32 + l31] = oa1[r];
    }
    if (half == 0) Cb[(p * 32 + l31) * 66 + 64] = rsf;
  } else {
    if (half == 0) Cb[(p * 32 + l31) * 66 + 65] = rsf;
  }
  __syncthreads();
  if (ks == 0) {
    unsigned short* Ob = AO + (size_t)(b * S + q0 + p * 32) * 1024 + h * 64;
#pragma unroll
    for (int r = 0; r < 16; ++r) {
      int row = (r & 3) + 8 * (r >> 2) + 4 * half;
      float p0 = Cb[(p * 32 + row) * 66 + l31];
      float p1 = Cb[(p * 32 + row) * 66 + 32 + l31];
      float inv = 1.0f / (Cb[(p * 32 + row) * 66 + 64] + Cb[(p * 32 + row) * 66 + 65]);
      Ob[(size_t)row * 1024 + l31] = f2bf((oa0[r] + p0) * inv);
      Ob[(size_t)row * 1024 + 32 + l31] = f2bf((oa1[r] + p1) * inv);
    }
  }
}

extern "C" void kernel_launch(void* const* d_in, const int* in_sizes, int n_in,
                              void* d_out, int out_size, void* d_ws, size_t ws_size,
                              hipStream_t stream) {
  const float* x  = (const float*)d_in[0];
  const float* Wq = (const float*)d_in[1];
  const float* bq = (const float*)d_in[2];
  const float* Wk = (const float*)d_in[3];
  const float* bk = (const float*)d_in[4];
  const float* Wv = (const float*)d_in[5];
  const float* bv = (const float*)d_in[6];
  const float* Wo = (const float*)d_in[7];
  const float* bo = (const float*)d_in[8];
  float* out = (float*)d_out;

  constexpr int B = 2, S = 2048, D = 1024, Dk = 64, H = 16;
  constexpr int M = B * S;          // 4096
  constexpr int NQKV = D + 2 * Dk;  // 1152

  char* ws = (char*)d_ws;
  unsigned short* xb   = (unsigned short*)ws; ws += (size_t)M * D * 2;
  unsigned short* QKVt = (unsigned short*)ws; ws += (size_t)NQKV * D * 2;
  unsigned short* Wot  = (unsigned short*)ws; ws += (size_t)D * D * 2;
  unsigned short* QKV  = (unsigned short*)ws; ws += (size_t)M * NQKV * 2;
  unsigned short* Vtb  = (unsigned short*)ws; ws += (size_t)B * Dk * S * 2;
  unsigned short* AO   = (unsigned short*)ws; ws += (size_t)M * D * 2;

  // 1. prep: convert x (z=4) + transpose/convert 4 weights (z=0..3)
  prep_kernel<<<dim3(32, 32, 5), 256, 0, stream>>>(x, Wq, Wk, Wv, Wo, xb, QKVt, Wot);

  // 2. fused QKV projection (64x64 tiles, BK=32 = 1152 blocks = 4.5/CU);
  //    epilogue scatters V^T and pre-scales Q by 0.125*log2e
  gemm_bf16_kernel<unsigned short, true><<<dim3(M / 64, NQKV / 64), 256, 0, stream>>>(
      xb, QKVt, bq, bk, bv, QKV, Vtb, M, NQKV, D);

  // 3. attention (split-K in-block: 512 blocks x 8 waves, in-register P,
  //    LDS dbuf + single barrier per tile)
  flash_attn_kernel<<<dim3(S / 128, H, B), 512, 0, stream>>>(QKV, Vtb, AO);

  // 4. output projection (64x64 tiles, BK=32 = 1024 blocks = 4/CU)
  gemm_bf16_kernel<float, false><<<dim3(M / 64, D / 64), 256, 0, stream>>>(
      AO, Wot, bo, nullptr, nullptr, out, nullptr, M, D, D);
}

// Round 15
// 164.766 us; speedup vs baseline: 1.0642x; 1.0149x over previous
//
#include <hip/hip_runtime.h>
#include <hip/hip_bf16.h>

typedef __attribute__((ext_vector_type(8))) short bf16x8;
typedef __attribute__((ext_vector_type(4))) float f32x4;
typedef __attribute__((ext_vector_type(16))) float f32x16;
typedef __attribute__((ext_vector_type(4))) unsigned short ushort4v;

// 0.125 * log2(e): folded into Q so attention probs are exp2(QK) directly
#define QSCALE 0.1803368801111204f

__device__ __forceinline__ unsigned short f2bf(float f) {
  union { float f; unsigned int u; } x; x.f = f;
  unsigned int u = x.u;
  unsigned int r = (u + 0x7fffu + ((u >> 16) & 1u)) >> 16;
  return (unsigned short)r;
}

// async global->LDS 16B copy (global_load_lds_dwordx4)
__device__ __forceinline__ void gll16(const unsigned short* g, unsigned short* l) {
  __builtin_amdgcn_global_load_lds(
      (const __attribute__((address_space(1))) unsigned int*)g,
      (__attribute__((address_space(3))) unsigned int*)l, 16, 0, 0);
}

// ---- fused prep: z<4 transpose+convert weights; z==4 convert x ----
__global__ __launch_bounds__(256) void prep_kernel(
    const float* __restrict__ x,
    const float* __restrict__ Wq, const float* __restrict__ Wk,
    const float* __restrict__ Wv, const float* __restrict__ Wo,
    unsigned short* __restrict__ xb,
    unsigned short* __restrict__ QKVt, unsigned short* __restrict__ Wot) {
  int z = blockIdx.z;
  if (z == 4) {  // x: 4096x1024 fp32 -> bf16
    size_t base = ((size_t)(blockIdx.y * 32 + blockIdx.x)) * 4096 + threadIdx.x * 16;
#pragma unroll
    for (int c = 0; c < 4; ++c) {
      float4 v = *(const float4*)(x + base + c * 4);
      ushort4v o = { f2bf(v.x), f2bf(v.y), f2bf(v.z), f2bf(v.w) };
      *(ushort4v*)(xb + base + c * 4) = o;
    }
    return;
  }
  __shared__ float t[32][33];
  const float* src;
  unsigned short* dst;
  int C, rowoff;
  if (z == 0)      { src = Wq; dst = QKVt; C = 1024; rowoff = 0; }
  else if (z == 1) { src = Wk; dst = QKVt; C = 64;   rowoff = 1024; }
  else if (z == 2) { src = Wv; dst = QKVt; C = 64;   rowoff = 1088; }
  else             { src = Wo; dst = Wot;  C = 1024; rowoff = 0; }
  int c0 = blockIdx.x * 32, r0 = blockIdx.y * 32;
  if (c0 >= C) return;
  int tx = threadIdx.x & 31, ty = threadIdx.x >> 5;
#pragma unroll
  for (int i = 0; i < 32; i += 8)
    t[ty + i][tx] = src[(size_t)(r0 + ty + i) * C + c0 + tx];
  __syncthreads();
#pragma unroll
  for (int i = 0; i < 32; i += 8)
    dst[(size_t)(rowoff + c0 + ty + i) * 1024 + r0 + tx] = f2bf(t[tx][ty + i]);
}

// ------- bf16 MFMA GEMM: C[M][N] = A[M][K] @ Bt[N][K]^T + bias -------
// R12/R14 structure (measured-best optimum) + T1 XCD-AWARE BLOCK SWIZZLE:
// default m-fastest dispatch round-robins panel-sharing blocks across all
// 8 XCDs, so each XCD's L2 sees the FULL A (8 MB) + B working set ->
// staged loads run at L3 latency (~400-600cy). Remap so XCD x owns
// m-tiles [8x, 8x+8) x ALL n-tiles: per-XCD set = 1 MB A-panel + 2.3 MB
// B = L2-resident -> staged-load latency ~halves. Bijection (nwg%8==0,
// nbx==64 for both GEMMs, m204 rule): linear orig = by*nbx+bx;
// mtile = ((orig&7)<<3)|((orig>>3)&7); ntile = orig>>6.
// Rest identical: 64x64 tile / 256 thr / 4 waves, BK=32, gll16 linear
// LDS, counted vmcnt(2) dbuf, T2 chunk-XOR swizzle.
// QKVMODE: per-column bias select + QSCALE on Q cols; V cols scatter V^T.
template <typename OutT, bool QKVMODE>
__global__ __launch_bounds__(256, 4) void gemm_bf16_kernel(
    const unsigned short* __restrict__ A, const unsigned short* __restrict__ Bt,
    const float* __restrict__ b0, const float* __restrict__ b1,
    const float* __restrict__ b2, OutT* __restrict__ C,
    unsigned short* __restrict__ Vt, int M, int N, int K) {
  __shared__ __align__(16) unsigned short As[2][64 * 32];
  __shared__ __align__(16) unsigned short Bs[2][64 * 32];
  int tid = threadIdx.x;
  int wid = tid >> 6, lane = tid & 63;
  int l15 = lane & 15, quad = lane >> 4;
  // T1 swizzle: requires gridDim.x == 64 and nwg % 8 == 0 (both GEMMs)
  int orig = blockIdx.y * gridDim.x + blockIdx.x;
  int mtile = ((orig & 7) << 3) | ((orig >> 3) & 7);
  int ntile = orig >> 6;
  int m0 = mtile * 64, n0 = ntile * 64;
  int mw = (wid >> 1) * 32, nw = (wid & 1) * 32;
  f32x4 acc[2][2];
#pragma unroll
  for (int i = 0; i < 2; i++)
#pragma unroll
    for (int j = 0; j < 2; j++)
#pragma unroll
      for (int e = 0; e < 4; ++e) acc[i][j][e] = 0.f;

  int u = tid;
  int srow = u >> 2;
  int gq = (u & 3) ^ ((srow >> 1) & 3);
  const unsigned short* Ag = A + (size_t)(m0 + srow) * K + gq * 8;
  const unsigned short* Bg = Bt + (size_t)(n0 + srow) * K + gq * 8;

  gll16(Ag, As[0] + u * 8);
  gll16(Bg, Bs[0] + u * 8);

  for (int k0 = 0; k0 < K; k0 += 32) {
    int cur = (k0 >> 5) & 1;
    if (k0 + 32 < K) {
      int nxt = cur ^ 1;
      gll16(Ag + k0 + 32, As[nxt] + u * 8);
      gll16(Bg + k0 + 32, Bs[nxt] + u * 8);
      asm volatile("s_waitcnt vmcnt(2)" ::: "memory");  // current tile done
    } else {
      asm volatile("s_waitcnt vmcnt(0)" ::: "memory");
    }
    __builtin_amdgcn_s_barrier();
    __builtin_amdgcn_sched_barrier(0);
    const unsigned short* Asb = As[cur];
    const unsigned short* Bsb = Bs[cur];
    bf16x8 af[2], bfr[2];
#pragma unroll
    for (int t = 0; t < 2; ++t) {
      int row = mw + t * 16 + l15;
      af[t] = *(const bf16x8*)(Asb + row * 32 + ((quad ^ ((row >> 1) & 3)) * 8));
    }
#pragma unroll
    for (int t = 0; t < 2; ++t) {
      int row = nw + t * 16 + l15;
      bfr[t] = *(const bf16x8*)(Bsb + row * 32 + ((quad ^ ((row >> 1) & 3)) * 8));
    }
#pragma unroll
    for (int mt = 0; mt < 2; ++mt)
#pragma unroll
      for (int nt = 0; nt < 2; ++nt)
        acc[mt][nt] = __builtin_amdgcn_mfma_f32_16x16x32_bf16(
            af[mt], bfr[nt], acc[mt][nt], 0, 0, 0);
    asm volatile("s_waitcnt lgkmcnt(0)" ::: "memory");
    __builtin_amdgcn_sched_barrier(0);
    __builtin_amdgcn_s_barrier();
  }
#pragma unroll
  for (int mt = 0; mt < 2; ++mt)
#pragma unroll
    for (int nt = 0; nt < 2; ++nt) {
      int col = n0 + nw + nt * 16 + l15;
      float bias, cs;
      if constexpr (QKVMODE) {
        bias = (col < 1024) ? b0[col] : ((col < 1088) ? b1[col - 1024] : b2[col - 1088]);
        cs = (col < 1024) ? QSCALE : 1.0f;
      } else {
        bias = b0[col];
        cs = 1.0f;
      }
#pragma unroll
      for (int r = 0; r < 4; ++r) {
        int row = m0 + mw + mt * 16 + quad * 4 + r;
        float v = (acc[mt][nt][r] + bias) * cs;
        if constexpr (sizeof(OutT) == 2)
          C[(size_t)row * N + col] = f2bf(v);
        else
          C[(size_t)row * N + col] = v;
        if constexpr (QKVMODE) {
          if (col >= 1088)  // scatter V^T for flash: Vt[b*64+d][s]
            Vt[((size_t)(row >> 11) * 64 + (col - 1088)) * 2048 + (row & 2047)] =
                f2bf(v);
        }
      }
    }
}

// ---------------- flash attention (MQA, split-K in-block) ----------------
// EXACT R12/R14 version (best measured: 44.6 us, 56 VGPR). T12 swapped-QK +
// in-register P; LDS double-buffer with ONE barrier per kt-tile (trailing
// barrier provably redundant under dbuf); T5 setprio around MFMA clusters.
__global__ __launch_bounds__(512, 2) void flash_attn_kernel(
    const unsigned short* __restrict__ QKV,  // [B*S][1152] bf16: Q|K|V
    const unsigned short* __restrict__ Vt,   // [B][64][2048] bf16
    unsigned short* __restrict__ AO) {       // [B*S][1024] bf16
  constexpr int S = 2048, LDQ = 1152;
  constexpr int PK = 72;
  // [tilebuf][slice][K=0/V=1][64*PK] = 73728 B
  __shared__ __align__(16) unsigned short smem[2][2][2][64 * PK];
  int tid = threadIdx.x;
  int wid = tid >> 6, lane = tid & 63;
  int l31 = lane & 31, half = lane >> 5;
  int p = wid & 3, ks = wid >> 2;
  int q0 = blockIdx.x * 128, h = blockIdx.y, b = blockIdx.z;

  // Q frags (MFMA B operand; n=q=l31, k(d)=s*16+half*8+j)
  const unsigned short* Qb =
      QKV + (size_t)(b * S + q0 + p * 32 + l31) * LDQ + h * 64 + half * 8;
  bf16x8 qf[4];
#pragma unroll
  for (int f = 0; f < 4; ++f) qf[f] = *(const bf16x8*)(Qb + f * 16);

  // staging role: 256 threads per slice sl; each stages 2 K + 2 V b128 chunks
  int u = tid & 255, sl = tid >> 8;
  int srow = u >> 2, sc = (u & 3) * 8;  // chunks at cols sc and sc+32
  const unsigned short* Kgb = QKV + ((size_t)b * S) * LDQ + 1024;
  const unsigned short* Vgb = Vt + ((size_t)(b * 64 + srow)) * 2048;

  f32x16 oa0, oa1;
#pragma unroll
  for (int r = 0; r < 16; ++r) { oa0[r] = 0.f; oa1[r] = 0.f; }
  float rs = 0.f;  // per-lane partial row-sum for q=l31

  int kb0 = sl * 1024;
  bf16x8 ka = *(const bf16x8*)(Kgb + (size_t)(kb0 + srow) * LDQ + sc);
  bf16x8 kc = *(const bf16x8*)(Kgb + (size_t)(kb0 + srow) * LDQ + sc + 32);
  bf16x8 va = *(const bf16x8*)(Vgb + kb0 + sc);
  bf16x8 vc = *(const bf16x8*)(Vgb + kb0 + sc + 32);

  for (int kt = 0; kt < 16; ++kt) {
    int tb = kt & 1;
    // stage this tile into buffer tb (both slices across the 512 threads)
    *(bf16x8*)(smem[tb][sl][0] + srow * PK + sc) = ka;
    *(bf16x8*)(smem[tb][sl][0] + srow * PK + sc + 32) = kc;
    *(bf16x8*)(smem[tb][sl][1] + srow * PK + sc) = va;
    *(bf16x8*)(smem[tb][sl][1] + srow * PK + sc + 32) = vc;
    __syncthreads();  // publishes tile kt; fences buffer tb for reuse
    if (kt + 1 < 16) {  // prefetch next tile; in flight across compute
      int kbn = sl * 1024 + (kt + 1) * 64;
      ka = *(const bf16x8*)(Kgb + (size_t)(kbn + srow) * LDQ + sc);
      kc = *(const bf16x8*)(Kgb + (size_t)(kbn + srow) * LDQ + sc + 32);
      va = *(const bf16x8*)(Vgb + kbn + sc);
      vc = *(const bf16x8*)(Vgb + kbn + sc + 32);
    }
    const unsigned short* Ksb = smem[tb][ks][0];
    const unsigned short* Vsb = smem[tb][ks][1];

    // S^T = K.Q^T : C col=q=l31, row=key=(r&3)+8*(r>>2)+4*half (+32*n2)
#pragma unroll
    for (int n2 = 0; n2 < 2; ++n2) {
      f32x16 sacc;
#pragma unroll
      for (int i = 0; i < 16; ++i) sacc[i] = 0.f;
      __builtin_amdgcn_s_setprio(1);
#pragma unroll
      for (int s = 0; s < 4; ++s) {
        bf16x8 kf =
            *(const bf16x8*)(Ksb + (n2 * 32 + l31) * PK + s * 16 + half * 8);
        sacc = __builtin_amdgcn_mfma_f32_32x32x16_bf16(kf, qf[s], sacc, 0, 0, 0);
      }
      __builtin_amdgcn_s_setprio(0);
      // two key-16-slices per n2: sg = n2*2 + t covers keys sg*16..+15
#pragma unroll
      for (int t = 0; t < 2; ++t) {
        float pr[8];
#pragma unroll
        for (int j = 0; j < 8; ++j) {
          pr[j] = __builtin_amdgcn_exp2f(sacc[t * 8 + j]);
          rs += pr[j];
        }
        unsigned w0A, w1A, w0B, w1B;
        asm("v_cvt_pk_bf16_f32 %0, %1, %2" : "=v"(w0A) : "v"(pr[0]), "v"(pr[1]));
        asm("v_cvt_pk_bf16_f32 %0, %1, %2" : "=v"(w1A) : "v"(pr[2]), "v"(pr[3]));
        asm("v_cvt_pk_bf16_f32 %0, %1, %2" : "=v"(w0B) : "v"(pr[4]), "v"(pr[5]));
        asm("v_cvt_pk_bf16_f32 %0, %1, %2" : "=v"(w1B) : "v"(pr[6]), "v"(pr[7]));
        asm volatile("v_permlane32_swap_b32 %0, %1" : "+v"(w0A), "+v"(w0B));
        asm volatile("v_permlane32_swap_b32 %0, %1" : "+v"(w1A), "+v"(w1B));
        union { unsigned u[4]; bf16x8 v; } afu;
        afu.u[0] = w0A; afu.u[1] = w1A; afu.u[2] = w0B; afu.u[3] = w1B;
        int sg = n2 * 2 + t;
        bf16x8 vf0 = *(const bf16x8*)(Vsb + (l31) * PK + sg * 16 + half * 8);
        bf16x8 vf1 = *(const bf16x8*)(Vsb + (32 + l31) * PK + sg * 16 + half * 8);
        __builtin_amdgcn_s_setprio(1);
        oa0 = __builtin_amdgcn_mfma_f32_32x32x16_bf16(afu.v, vf0, oa0, 0, 0, 0);
        oa1 = __builtin_amdgcn_mfma_f32_32x32x16_bf16(afu.v, vf1, oa1, 0, 0, 0);
        __builtin_amdgcn_s_setprio(0);
      }
    }
    // no trailing barrier: next iter writes the OTHER buffer; its top
    // barrier orders this iter's reads before any overwrite of this buffer
  }

  // full row-sum for q=l31: add partner half's key-subset
  float rsf = rs + __shfl_xor(rs, 32, 64);

  // split-K combine via LDS (aliases buffer 0 region; the kt=15 top
  // barrier ordered all buffer-0 reads (kt=14) before these writes)
  float* Cb = (float*)smem;  // [4 groups][32 q][66]: d0..63, rs_ks1, rs_ks0
  if (ks == 1) {
#pragma unroll
    for (int r = 0; r < 16; ++r) {
      int row = (r & 3) + 8 * (r >> 2) + 4 * half;
      Cb[(p * 32 + row) * 66 + l31] = oa0[r];
      Cb[(p * 32 + row) * 66 + 32 + l31] = oa1[r];
    }
    if (half == 0) Cb[(p * 32 + l31) * 66 + 64] = rsf;
  } else {
    if (half == 0) Cb[(p * 32 + l31) * 66 + 65] = rsf;
  }
  __syncthreads();
  if (ks == 0) {
    unsigned short* Ob = AO + (size_t)(b * S + q0 + p * 32) * 1024 + h * 64;
#pragma unroll
    for (int r = 0; r < 16; ++r) {
      int row = (r & 3) + 8 * (r >> 2) + 4 * half;
      float p0 = Cb[(p * 32 + row) * 66 + l31];
      float p1 = Cb[(p * 32 + row) * 66 + 32 + l31];
      float inv = 1.0f / (Cb[(p * 32 + row) * 66 + 64] + Cb[(p * 32 + row) * 66 + 65]);
      Ob[(size_t)row * 1024 + l31] = f2bf((oa0[r] + p0) * inv);
      Ob[(size_t)row * 1024 + 32 + l31] = f2bf((oa1[r] + p1) * inv);
    }
  }
}

extern "C" void kernel_launch(void* const* d_in, const int* in_sizes, int n_in,
                              void* d_out, int out_size, void* d_ws, size_t ws_size,
                              hipStream_t stream) {
  const float* x  = (const float*)d_in[0];
  const float* Wq = (const float*)d_in[1];
  const float* bq = (const float*)d_in[2];
  const float* Wk = (const float*)d_in[3];
  const float* bk = (const float*)d_in[4];
  const float* Wv = (const float*)d_in[5];
  const float* bv = (const float*)d_in[6];
  const float* Wo = (const float*)d_in[7];
  const float* bo = (const float*)d_in[8];
  float* out = (float*)d_out;

  constexpr int B = 2, S = 2048, D = 1024, Dk = 64, H = 16;
  constexpr int M = B * S;          // 4096
  constexpr int NQKV = D + 2 * Dk;  // 1152

  char* ws = (char*)d_ws;
  unsigned short* xb   = (unsigned short*)ws; ws += (size_t)M * D * 2;
  unsigned short* QKVt = (unsigned short*)ws; ws += (size_t)NQKV * D * 2;
  unsigned short* Wot  = (unsigned short*)ws; ws += (size_t)D * D * 2;
  unsigned short* QKV  = (unsigned short*)ws; ws += (size_t)M * NQKV * 2;
  unsigned short* Vtb  = (unsigned short*)ws; ws += (size_t)B * Dk * S * 2;
  unsigned short* AO   = (unsigned short*)ws; ws += (size_t)M * D * 2;

  // 1. prep: convert x (z=4) + transpose/convert 4 weights (z=0..3)
  prep_kernel<<<dim3(32, 32, 5), 256, 0, stream>>>(x, Wq, Wk, Wv, Wo, xb, QKVt, Wot);

  // 2. fused QKV projection (64x64 tiles, BK=32 = 1152 blocks = 4.5/CU,
  //    XCD-swizzled); epilogue scatters V^T and pre-scales Q
  gemm_bf16_kernel<unsigned short, true><<<dim3(M / 64, NQKV / 64), 256, 0, stream>>>(
      xb, QKVt, bq, bk, bv, QKV, Vtb, M, NQKV, D);

  // 3. attention (split-K in-block: 512 blocks x 8 waves, in-register P,
  //    LDS dbuf + single barrier per tile)
  flash_attn_kernel<<<dim3(S / 128, H, B), 512, 0, stream>>>(QKV, Vtb, AO);

  // 4. output projection (64x64 tiles, BK=32 = 1024 blocks = 4/CU,
  //    XCD-swizzled)
  gemm_bf16_kernel<float, false><<<dim3(M / 64, D / 64), 256, 0, stream>>>(
      AO, Wot, bo, nullptr, nullptr, out, nullptr, M, D, D);
}